// Round 4
// baseline (232.571 us; speedup 1.0000x reference)
//
#include <hip/hip_runtime.h>
#include <math.h>

// Pipeline:  y[b,i,j,0:16] = patch(b,i,j) · B + c   (affine collapse of FFT→ComplexDense→iFFT→Re)
//            out = subsample_odd( BN( dwconv3x3(y) ) )
//
// GEMM via v_mfma_f32_16x16x32_f16, A-fragments loaded DIRECTLY from global x
// (no LDS, no barriers): lane l owns patch m=l&15; for k-chunk t its 8 elements
// k = 32t + 8*(l>>4) + i are 8 consecutive floats of one input row. B is
// precomputed straight into MFMA-fragment order (f16 blob in ws).
//
// ws layout (floats):
//   [0    .. 15  ]  c[16]
//   [32   .. 2079]  Bfrag: 4096 f16 = 8 t-chunks x 64 lanes x 8 f16
//   [2080 .. +2M ]  y[2][256][256][16] f32

typedef _Float16 f16x8 __attribute__((ext_vector_type(8)));
typedef float    f32x4 __attribute__((ext_vector_type(4)));

constexpr int C_OFF  = 0;
constexpr int BF_OFF = 32;
constexpr int Y_OFF  = 2080;

#define TWO_PI_OVER_256 0.0245436926f
#define BN_EPS 1e-5f

// ---------------- A: fused precomp: V (per-block, redundant) -> B fragment blob + c ------------
// V[k][d] = (1/16) sum_j W[k][j] e^{+2pi i jd/16}
// B[n][d] = sum_k ReV[k][d] cos(2pi kn/256) + ImV[k][d] sin(2pi kn/256)
// Fragment position for (n,d):  t=n>>5, lane=d+16*((n>>3)&3), i=n&7 -> blob[(t*64+lane)*8+i]
__global__ __launch_bounds__(256) void k_precomp(
    const float* __restrict__ Wr, const float* __restrict__ br,
    const float* __restrict__ Wi, const float* __restrict__ bi,
    float* __restrict__ ws) {
  __shared__ float cs[256], sn[256];
  __shared__ float ReV[4096], ImV[4096];
  int tid = threadIdx.x;
  float s_, c_;
  sincosf((float)tid * TWO_PI_OVER_256, &s_, &c_);
  cs[tid] = c_; sn[tid] = s_;
  __syncthreads();

  // Phase 1: every block computes the full V into its LDS (65K FLOP, trivial).
#pragma unroll
  for (int ph = 0; ph < 16; ++ph) {
    int tg = ph * 256 + tid;           // 0..4095
    int k = tg >> 4, d = tg & 15;
    float re = 0.f, im = 0.f;
#pragma unroll
    for (int j = 0; j < 16; ++j) {
      float wr = Wr[k * 16 + j], wi = Wi[k * 16 + j];
      int idx = ((j * d) & 15) << 4;   // angle 2pi*(jd)/16
      float cc = cs[idx], ss = sn[idx];
      re += wr * cc - wi * ss;
      im += wr * ss + wi * cc;
    }
    ReV[tg] = re * 0.0625f;
    ImV[tg] = im * 0.0625f;
  }
  __syncthreads();

  // Phase 2: this block's 1/64 slice of B, 4 lanes per (n,d) entry.
  int e = tid >> 2, q = tid & 3;
  int eg = blockIdx.x * 64 + e;        // 0..4095
  int n = eg >> 4, d = eg & 15;
  int m = (q * n) & 255;
  int step = (n << 2) & 255;
  float acc = 0.f;
#pragma unroll 4
  for (int kk = 0; kk < 64; ++kk) {
    int k = q + (kk << 2);
    acc = fmaf(ReV[k * 16 + d], cs[m], acc);
    acc = fmaf(ImV[k * 16 + d], sn[m], acc);
    m = (m + step) & 255;
  }
  acc += __shfl_xor(acc, 1);
  acc += __shfl_xor(acc, 2);
  if (q == 0) {
    int t = n >> 5, hh = (n >> 3) & 3, ii = n & 7;
    _Float16* bf = (_Float16*)(ws + BF_OFF);
    bf[((t * 64 + (d + (hh << 4))) << 3) + ii] = (_Float16)acc;
  }

  // c[d] (block 0 only)
  if (blockIdx.x == 0 && tid < 16) {
    float accc = 0.f;
#pragma unroll
    for (int j = 0; j < 16; ++j) {
      float cr  = br[j] - bi[j];       // Re(beta)
      float ci2 = br[j] + bi[j];       // Im(beta)
      int idx = ((j * tid) & 15) << 4;
      accc += cr * cs[idx] - ci2 * sn[idx];
    }
    ws[C_OFF + tid] = accc * 0.0625f;
  }
}

// ---------------- B: patch GEMM via MFMA, direct-to-register A ---------------------------------
// wave = one 16-patch tile (16 consecutive j in one patch-row i). 8192 waves total.
__global__ __launch_bounds__(256) void k_gemm(const float* __restrict__ x,
                                              float* __restrict__ ws) {
  int tid = threadIdx.x;
  int l   = tid & 63;
  int wv  = (blockIdx.x << 2) + (tid >> 6);  // 0..8191
  int j16 = wv & 15;
  int i   = (wv >> 4) & 255;
  int b   = wv >> 12;
  int m   = l & 15;          // A: patch-in-tile; B/D: channel
  int h   = l >> 4;

  // B fragments (coalesced, L2-resident)
  const f16x8* bfr = (const f16x8*)(ws + BF_OFF);
  f16x8 bf[8];
#pragma unroll
  for (int t = 0; t < 8; ++t) bf[t] = bfr[(t << 6) + l];

  // A: issue all 16 global float4 loads
  const float* ab = x + (b * 4096 + i * 16 + (h >> 1)) * 4096
                      + (j16 << 8) + (m << 4) + ((h & 1) << 3);
  float4 ar[8][2];
#pragma unroll
  for (int t = 0; t < 8; ++t) {
    ar[t][0] = *reinterpret_cast<const float4*>(ab + t * 8192);
    ar[t][1] = *reinterpret_cast<const float4*>(ab + t * 8192 + 4);
  }

  f32x4 acc = {0.f, 0.f, 0.f, 0.f};
#pragma unroll
  for (int t = 0; t < 8; ++t) {
    f16x8 a;
    a[0] = (_Float16)ar[t][0].x; a[1] = (_Float16)ar[t][0].y;
    a[2] = (_Float16)ar[t][0].z; a[3] = (_Float16)ar[t][0].w;
    a[4] = (_Float16)ar[t][1].x; a[5] = (_Float16)ar[t][1].y;
    a[6] = (_Float16)ar[t][1].z; a[7] = (_Float16)ar[t][1].w;
    acc = __builtin_amdgcn_mfma_f32_16x16x32_f16(a, bf[t], acc, 0, 0, 0);
  }

  // epilogue: D[row=4h+r][col=m] -> y[pix][ch] + c[ch]
  float cv = ws[C_OFF + m];
  int pixbase = (b << 16) + (i << 8) + (j16 << 4);
  float* y = ws + Y_OFF;
#pragma unroll
  for (int r = 0; r < 4; ++r) {
    int p = (h << 2) + r;
    y[(pixbase + p) * 16 + m] = acc[r] + cv;
  }
}

// ---------------- C: depthwise 3x3 SAME + BN + odd-index subsample -----------------------------
// thread = (output pixel, 2 channels). 262144 threads -> 16 waves/CU.
__global__ __launch_bounds__(256) void k_conv_bn(
    const float* __restrict__ ws, const float* __restrict__ dwk,
    const float* __restrict__ dwb, const float* __restrict__ gamma,
    const float* __restrict__ beta, const float* __restrict__ mmean,
    const float* __restrict__ mvar, float* __restrict__ out) {
  int g = blockIdx.x * 256 + threadIdx.x;
  int qq = g & 7;                           // channel pair 0..7
  int pg = g >> 3;                          // 0..32767
  int oj = pg & 127, oi = (pg >> 7) & 127, b = pg >> 14;
  int ci = 2 * oi + 1, cj = 2 * oj + 1;     // nearest-neighbor: odd indices
  const float* yb = ws + Y_OFF + b * (256 * 256 * 16);

  float2 acc = {0.f, 0.f};
#pragma unroll
  for (int kh = 0; kh < 3; ++kh) {
    int r = ci + kh - 1;
    if (r > 255) continue;                  // SAME zero-pad (r>=0 always)
#pragma unroll
    for (int kw = 0; kw < 3; ++kw) {
      int cc = cj + kw - 1;
      if (cc > 255) continue;
      float2 yv = *reinterpret_cast<const float2*>(yb + ((r << 8) + cc) * 16 + (qq << 1));
      float2 kv = *reinterpret_cast<const float2*>(dwk + ((kh * 3 + kw) << 4) + (qq << 1));
      acc.x = fmaf(yv.x, kv.x, acc.x);
      acc.y = fmaf(yv.y, kv.y, acc.y);
    }
  }

  float2 gv  = *reinterpret_cast<const float2*>(gamma + (qq << 1));
  float2 bv  = *reinterpret_cast<const float2*>(beta  + (qq << 1));
  float2 mv  = *reinterpret_cast<const float2*>(mmean + (qq << 1));
  float2 vv  = *reinterpret_cast<const float2*>(mvar  + (qq << 1));
  float2 dbv = *reinterpret_cast<const float2*>(dwb   + (qq << 1));
  float2 o;
  o.x = (acc.x + dbv.x - mv.x) * (gv.x * rsqrtf(vv.x + BN_EPS)) + bv.x;
  o.y = (acc.y + dbv.y - mv.y) * (gv.y * rsqrtf(vv.y + BN_EPS)) + bv.y;
  *reinterpret_cast<float2*>(out + (pg << 4) + (qq << 1)) = o;
}

extern "C" void kernel_launch(void* const* d_in, const int* in_sizes, int n_in,
                              void* d_out, int out_size, void* d_ws, size_t ws_size,
                              hipStream_t stream) {
  const float* x     = (const float*)d_in[0];
  const float* Wr    = (const float*)d_in[1];
  const float* br    = (const float*)d_in[2];
  const float* Wi    = (const float*)d_in[3];
  const float* bi    = (const float*)d_in[4];
  const float* dwk   = (const float*)d_in[5];
  const float* dwb   = (const float*)d_in[6];
  const float* gamma = (const float*)d_in[7];
  const float* beta  = (const float*)d_in[8];
  const float* mmean = (const float*)d_in[9];
  const float* mvar  = (const float*)d_in[10];
  float* ws  = (float*)d_ws;
  float* out = (float*)d_out;

  k_precomp<<<64,   256, 0, stream>>>(Wr, br, Wi, bi, ws);
  k_gemm   <<<2048, 256, 0, stream>>>(x, ws);
  k_conv_bn<<<1024, 256, 0, stream>>>(ws, dwk, dwb, gamma, beta, mmean, mvar, out);
}